// Round 1
// baseline (253.184 us; speedup 1.0000x reference)
//
#include <hip/hip_runtime.h>
#include <math.h>

// Problem constants
#define BB 128
#define HH 256
#define WW 256
#define HW 65536            // H*W floats per channel
#define S_F2_PER_B 98304    // 3*HW floats / 2 -> float2 stride per batch in out
#define S_OFF_F2 32768      // ch1 start (HW floats) in float2 units

__device__ __forceinline__ float2 cadd(float2 a, float2 b){ return make_float2(a.x+b.x, a.y+b.y); }
__device__ __forceinline__ float2 csub(float2 a, float2 b){ return make_float2(a.x-b.x, a.y-b.y); }
__device__ __forceinline__ float2 cmul(float2 a, float2 b){ return make_float2(a.x*b.x - a.y*b.y, a.x*b.y + a.y*b.x); }
__device__ __forceinline__ int rev8(int x){ return (int)(__brev((unsigned)x) >> 24); }

__device__ __forceinline__ void build_tw(float2* tw, int tid) {
    if (tid < 128) {
        float s, c;
        __sincosf(-6.28318530717958647692f * (float)tid / 256.0f, &s, &c);
        tw[tid] = make_float2(c, s);
    }
}

// ---------------- Pass 1: row forward DIF (natural w -> bit-reversed w) ----------------
// 2 rows per block, 256 threads (128 threads per FFT, 1 butterfly/thread/stage)
__global__ __launch_bounds__(256) void k_row_fwd(const float* __restrict__ x, float* __restrict__ out) {
    __shared__ float2 d[2][256];
    __shared__ float2 tw[128];
    int tid = threadIdx.x;
    int pair = blockIdx.x;               // [0, B*H/2)
    build_tw(tw, tid);
    int base_in = pair * 512;
    d[0][tid] = make_float2(x[base_in + tid], 0.0f);
    d[1][tid] = make_float2(x[base_in + 256 + tid], 0.0f);
    __syncthreads();
    int which = tid >> 7;
    int t = tid & 127;
    float2* dd = d[which];
    for (int s = 7; s >= 0; --s) {
        int half = 1 << s;
        int j = t & (half - 1);
        int idx = ((t >> s) << (s + 1)) + j;
        float2 u = dd[idx];
        float2 v = dd[idx + half];
        float2 w = tw[j << (7 - s)];
        dd[idx] = cadd(u, v);
        dd[idx + half] = cmul(csub(u, v), w);
        __syncthreads();
    }
    int row = pair * 2;
    int b = row >> 8;
    int h0 = row & 255;
    float2* S = (float2*)out;
    int sb = b * S_F2_PER_B + S_OFF_F2;
    S[sb + h0 * 256 + tid]       = d[0][tid];
    S[sb + (h0 + 1) * 256 + tid] = d[1][tid];
}

// ---------------- Pass 2: column fwd DIF + mask + column inv DIT (in place) ----------------
// blockIdx.x = column group (16 cols), blockIdx.y = batch. 256 threads.
__global__ __launch_bounds__(256) void k_col(float* __restrict__ out,
                                             const int* __restrict__ cid,
                                             const float* __restrict__ pi) {
    __shared__ float2 tile[256 * 17];   // [h][c] padded stride 17
    __shared__ float2 tw[128];
    __shared__ float sPI[64];
    int tid = threadIdx.x;
    int cg = blockIdx.x;                // 0..15
    int b  = blockIdx.y;                // 0..127
    build_tw(tw, tid);
    if (tid < 64) sPI[tid] = pi[(((b + 64) & 127) << 6) + tid];
    float2* S = (float2*)out;
    int sb = b * S_F2_PER_B + S_OFF_F2;
    int c0 = cg * 16;
    #pragma unroll
    for (int k = 0; k < 16; ++k) {
        int f = tid + k * 256;
        int h = f >> 4, c = f & 15;
        tile[h * 17 + c] = S[sb + h * 256 + c0 + c];
    }
    __syncthreads();
    int c  = tid & 15;
    int jb = tid >> 4;                  // 0..15
    // forward DIF along h
    for (int s = 7; s >= 0; --s) {
        int half = 1 << s;
        #pragma unroll
        for (int k = 0; k < 8; ++k) {
            int t = jb + k * 16;        // 0..127
            int j = t & (half - 1);
            int idx = ((t >> s) << (s + 1)) + j;
            float2 u = tile[idx * 17 + c];
            float2 v = tile[(idx + half) * 17 + c];
            float2 w = tw[j << (7 - s)];
            tile[idx * 17 + c] = cadd(u, v);
            tile[(idx + half) * 17 + c] = cmul(csub(u, v), w);
        }
        __syncthreads();
    }
    // mask multiply (storage order is bit-reversed in both axes; shifts folded as +128)
    #pragma unroll
    for (int k = 0; k < 16; ++k) {
        int f = tid + k * 256;
        int a = f >> 4, cc = f & 15;
        int h2 = (rev8(a) + 128) & 255;
        int w2 = (rev8(c0 + cc) + 128) & 255;
        int cv = cid[h2 * 256 + w2];
        float m = (cv < 64) ? sPI[cv] : 1.0f;
        float2 v = tile[a * 17 + cc];
        tile[a * 17 + cc] = make_float2(v.x * m, v.y * m);
    }
    __syncthreads();
    // inverse DIT along h (bit-reversed in -> natural out), conjugated twiddles
    for (int s = 0; s <= 7; ++s) {
        int half = 1 << s;
        #pragma unroll
        for (int k = 0; k < 8; ++k) {
            int t = jb + k * 16;
            int j = t & (half - 1);
            int idx = ((t >> s) << (s + 1)) + j;
            float2 w = tw[j << (7 - s)]; w.y = -w.y;
            float2 u = tile[idx * 17 + c];
            float2 v = cmul(tile[(idx + half) * 17 + c], w);
            tile[idx * 17 + c] = cadd(u, v);
            tile[(idx + half) * 17 + c] = csub(u, v);
        }
        __syncthreads();
    }
    #pragma unroll
    for (int k = 0; k < 16; ++k) {
        int f = tid + k * 256;
        int h = f >> 4, cc = f & 15;
        S[sb + h * 256 + c0 + cc] = tile[h * 17 + cc];
    }
}

// ---------------- Pass 3: row inverse DIT + abs -> y into ch0 ----------------
__global__ __launch_bounds__(256) void k_row_inv(float* __restrict__ out) {
    __shared__ float2 d[2][256];
    __shared__ float2 tw[128];
    int tid = threadIdx.x;
    int pair = blockIdx.x;
    build_tw(tw, tid);
    int row = pair * 2;
    int b = row >> 8;
    int h0 = row & 255;
    float2* S = (float2*)out;
    int sb = b * S_F2_PER_B + S_OFF_F2;
    d[0][tid] = S[sb + h0 * 256 + tid];
    d[1][tid] = S[sb + (h0 + 1) * 256 + tid];
    __syncthreads();
    int which = tid >> 7;
    int t = tid & 127;
    float2* dd = d[which];
    for (int s = 0; s <= 7; ++s) {
        int half = 1 << s;
        int j = t & (half - 1);
        int idx = ((t >> s) << (s + 1)) + j;
        float2 w = tw[j << (7 - s)]; w.y = -w.y;
        float2 u = dd[idx];
        float2 v = cmul(dd[idx + half], w);
        dd[idx] = cadd(u, v);
        dd[idx + half] = csub(u, v);
        __syncthreads();
    }
    const float scale = 1.0f / 65536.0f;   // 1/(H*W) from ifft2
    float2 v0 = d[0][tid];
    float2 v1 = d[1][tid];
    float y0 = sqrtf(v0.x * v0.x + v0.y * v0.y) * scale;
    float y1 = sqrtf(v1.x * v1.x + v1.y * v1.y) * scale;
    out[b * 196608 + h0 * 256 + tid]       = y0;   // ch0 region used as y staging
    out[b * 196608 + (h0 + 1) * 256 + tid] = y1;
}

// ---------------- Pass 4: finalize: ch0=x, ch1=y, ch2=|y-x|, copy PI tail ----------------
__global__ __launch_bounds__(256) void k_final(const float* __restrict__ x,
                                               const float* __restrict__ pi,
                                               float* __restrict__ out) {
    int i = blockIdx.x * 256 + threadIdx.x;     // float4 index over B*HW/4 = 2097152
    const float4* x4 = (const float4*)x;
    float4* o4 = (float4*)out;
    int b = i >> 14;               // / (HW/4)
    int r = i & 16383;
    int ch0 = b * 49152 + r;       // 3*HW/4 per batch
    float4 y  = o4[ch0];
    float4 xv = x4[i];
    float4 df;
    df.x = fabsf(y.x - xv.x);
    df.y = fabsf(y.y - xv.y);
    df.z = fabsf(y.z - xv.z);
    df.w = fabsf(y.w - xv.w);
    o4[ch0]         = xv;
    o4[ch0 + 16384] = y;
    o4[ch0 + 32768] = df;
    if (i < 2048) {                // PI tail: 8192 floats
        const float4* p4 = (const float4*)pi;
        o4[6291456 + i] = p4[i];
    }
}

extern "C" void kernel_launch(void* const* d_in, const int* in_sizes, int n_in,
                              void* d_out, int out_size, void* d_ws, size_t ws_size,
                              hipStream_t stream) {
    const float* x  = (const float*)d_in[0];
    const float* pi = (const float*)d_in[1];
    const int*  cid = (const int*)d_in[2];
    float* out = (float*)d_out;
    (void)d_ws; (void)ws_size; (void)in_sizes; (void)n_in; (void)out_size;

    k_row_fwd<<<BB * HH / 2, 256, 0, stream>>>(x, out);
    k_col<<<dim3(16, BB), 256, 0, stream>>>(out, cid, pi);
    k_row_inv<<<BB * HH / 2, 256, 0, stream>>>(out);
    k_final<<<8192, 256, 0, stream>>>(x, pi, out);
}

// Round 2
// 207.939 us; speedup vs baseline: 1.2176x; 1.2176x over previous
//
#include <hip/hip_runtime.h>
#include <math.h>

#define BB 128
#define HH 256
#define WW 256
#define HW 65536
#define OUT_B_STRIDE 196608   // 3*HW floats per batch in out

__device__ __forceinline__ float2 cadd(float2 a, float2 b){ return make_float2(a.x+b.x, a.y+b.y); }
__device__ __forceinline__ float2 csub(float2 a, float2 b){ return make_float2(a.x-b.x, a.y-b.y); }

// a * b  (INV=false)  or  a * conj(b)  (INV=true)
template<bool INV>
__device__ __forceinline__ float2 cmul_t(float2 a, float2 b){
  if (INV) return make_float2(a.x*b.x + a.y*b.y, a.y*b.x - a.x*b.y);
  return make_float2(a.x*b.x - a.y*b.y, a.x*b.y + a.y*b.x);
}

template<bool INV>
__device__ __forceinline__ void fft4(float2&a,float2&b,float2&c,float2&d){
  float2 t0 = cadd(a,c), t1 = csub(a,c);
  float2 t2 = cadd(b,d), t3 = csub(b,d);
  float2 t3r = INV ? make_float2(-t3.y, t3.x) : make_float2(t3.y, -t3.x); // (+/-)i * t3
  a = cadd(t0,t2);
  b = cadd(t1,t3r);
  c = csub(t0,t2);
  d = csub(t1,t3r);
}

// 16-point DFT, natural-in natural-out, exponent e^{-2pi i jq/16} (conj if INV).
template<bool INV>
__device__ __forceinline__ void fft16(float2 x[16]){
  #pragma unroll
  for (int j0=0;j0<4;++j0) fft4<INV>(x[j0], x[j0+4], x[j0+8], x[j0+12]);
  // twiddle w16^{j0*q0} (forward values; cmul_t conjugates for INV)
  const float WR[10] = {1.f, 0.923879533f, 0.707106781f, 0.382683432f, 0.f,
                        0.f, -0.707106781f, 0.f, 0.f, -0.923879533f};
  const float WI[10] = {0.f, -0.382683432f, -0.707106781f, -0.923879533f, -1.f,
                        0.f, -0.707106781f, 0.f, 0.f, 0.382683432f};
  #pragma unroll
  for (int q0=1;q0<4;++q0)
    #pragma unroll
    for (int j0=1;j0<4;++j0){
      int k = j0*q0;
      x[j0+4*q0] = cmul_t<INV>(x[j0+4*q0], make_float2(WR[k], WI[k]));
    }
  #pragma unroll
  for (int q0=0;q0<4;++q0) fft4<INV>(x[4*q0], x[4*q0+1], x[4*q0+2], x[4*q0+3]);
  // permute: y[q0+4q1] currently at slot [4q0+q1] -> natural (compile-time renames)
  float2 t[16];
  #pragma unroll
  for (int q0=0;q0<4;++q0)
    #pragma unroll
    for (int q1=0;q1<4;++q1) t[q0+4*q1] = x[4*q0+q1];
  #pragma unroll
  for (int i=0;i<16;++i) x[i]=t[i];
}

__device__ __forceinline__ void build_tw256(float2* tw, int tid){
  float s,c;
  __sincosf(-6.28318530717958647692f * (float)tid / 256.0f, &s, &c);
  tw[tid] = make_float2(c, s);   // e^{-2pi i tid/256}
}

// ---------------- K1: row forward FFT ----------------
// 16 rows/block, 16 threads/row. Four-step 256 = 16x16.
// Storage: S[b][h][p] float2, p = s*16 + k1 encodes w_freq = 16*k1 + s (digit-permuted).
__global__ __launch_bounds__(256) void k_row_fwd(const float* __restrict__ x,
                                                 float2* __restrict__ S, int bstride){
  __shared__ float2 tw[256];
  __shared__ float2 zbuf[16*273];
  int tid = threadIdx.x;
  int t = tid & 15, r = tid >> 4;
  build_tw256(tw, tid);
  int row = blockIdx.x*16 + r;            // [0, B*H)
  const float* xr = x + (size_t)row*256;
  float2 X[16];
  #pragma unroll
  for (int j=0;j<16;++j) X[j] = make_float2(xr[16*j + t], 0.f);
  __syncthreads();                        // tw ready
  fft16<false>(X);                        // over j
  #pragma unroll
  for (int q=0;q<16;++q) X[q] = cmul_t<false>(X[q], tw[t*q]);
  #pragma unroll
  for (int q=0;q<16;++q) zbuf[r*273 + q*17 + t] = X[q];
  __syncthreads();
  float2 Y[16];
  #pragma unroll
  for (int tt=0;tt<16;++tt) Y[tt] = zbuf[r*273 + t*17 + tt];   // s = t (phase-2 index)
  fft16<false>(Y);                        // Y[k1] = X256[16k1 + s]
  int b = row >> 8, h = row & 255;
  float4* dst = (float4*)(S + (size_t)b*bstride + h*256 + t*16);
  #pragma unroll
  for (int k=0;k<8;++k)
    dst[k] = make_float4(Y[2*k].x, Y[2*k].y, Y[2*k+1].x, Y[2*k+1].y);
}

// ---------------- K2: column fwd + mask + column inv (in place) ----------------
__global__ __launch_bounds__(256) void k_col(float2* __restrict__ S, int bstride,
                                             const int* __restrict__ cid,
                                             const float* __restrict__ pi){
  __shared__ float2 tw[256];
  __shared__ float2 zbuf[16*273];
  __shared__ float sPI[64];
  int tid = threadIdx.x;
  int c = tid & 15, t = tid >> 4;
  int cg = blockIdx.x, b = blockIdx.y;
  build_tw256(tw, tid);
  if (tid < 64) sPI[tid] = pi[(((b + 64) & 127) << 6) + tid];  // fftshift batch roll
  float2* Sb = S + (size_t)b*bstride;
  int p = cg*16 + c;
  float2 X[16];
  #pragma unroll
  for (int j=0;j<16;++j) X[j] = Sb[(16*j + t)*256 + p];
  __syncthreads();
  fft16<false>(X);
  #pragma unroll
  for (int q=0;q<16;++q) X[q] = cmul_t<false>(X[q], tw[t*q]);
  #pragma unroll
  for (int q=0;q<16;++q) zbuf[c*273 + q*17 + t] = X[q];
  __syncthreads();
  int s = t;
  float2 Y[16];
  #pragma unroll
  for (int tt=0;tt<16;++tt) Y[tt] = zbuf[c*273 + s*17 + tt];
  fft16<false>(Y);                         // Y[k1] at h_freq = 16*k1 + s
  // mask (fftshift folded as +128 on both axes); column w = 16*c + cg
  int w2 = ((16*c + cg) + 128) & 255;
  #pragma unroll
  for (int k1=0;k1<16;++k1){
    int h2 = (16*k1 + s + 128) & 255;
    int cv = cid[h2*256 + w2];
    float m = (cv < 64) ? sPI[cv] : 1.0f;
    Y[k1].x *= m; Y[k1].y *= m;
  }
  __syncthreads();                          // zbuf phase-1 reads done
  fft16<true>(Y);                           // over k1 -> U[t] natural
  #pragma unroll
  for (int u=0;u<16;++u) Y[u] = cmul_t<true>(Y[u], tw[u*s]);
  #pragma unroll
  for (int u=0;u<16;++u) zbuf[c*273 + u*17 + s] = Y[u];
  __syncthreads();
  float2 R[16];
  #pragma unroll
  for (int k0=0;k0<16;++k0) R[k0] = zbuf[c*273 + t*17 + k0];
  fft16<true>(R);                           // register j = column sample at h = 16j + t
  #pragma unroll
  for (int j=0;j<16;++j) Sb[(16*j + t)*256 + p] = R[j];
}

// ---------------- K3 (fused): row inverse + abs + finalize ----------------
__global__ __launch_bounds__(256) void k_row_inv_fused(const float2* __restrict__ S, int bstride,
                                                       const float* __restrict__ x,
                                                       const float* __restrict__ pi,
                                                       float* __restrict__ out){
  __shared__ float2 tw[256];
  __shared__ float2 zbuf[16*273];
  int tid = threadIdx.x;
  int s = tid & 15, r = tid >> 4;
  int slice = blockIdx.x, b = blockIdx.y;
  build_tw256(tw, tid);
  int h = slice*16 + r;
  const float4* src4 = (const float4*)(S + (size_t)b*bstride + h*256 + s*16);
  float2 X[16];
  #pragma unroll
  for (int k=0;k<8;++k){
    float4 v = src4[k];
    X[2*k]   = make_float2(v.x, v.y);
    X[2*k+1] = make_float2(v.z, v.w);
  }
  __syncthreads();
  fft16<true>(X);                           // over k1 -> U[t]
  #pragma unroll
  for (int u=0;u<16;++u) X[u] = cmul_t<true>(X[u], tw[u*s]);
  #pragma unroll
  for (int u=0;u<16;++u) zbuf[r*273 + u*17 + s] = X[u];
  __syncthreads();
  int t = tid & 15;
  float2 R[16];
  #pragma unroll
  for (int k0=0;k0<16;++k0) R[k0] = zbuf[r*273 + t*17 + k0];
  fft16<true>(R);                           // register j = time sample n = 16j + t
  const float scale = 1.0f/65536.0f;        // 1/(H*W) from ifft2
  const float* xr = x + (size_t)b*HW + h*256;
  float* o = out + (size_t)b*OUT_B_STRIDE + h*256;
  #pragma unroll
  for (int j=0;j<16;++j){
    int n = 16*j + t;
    float y = sqrtf(R[j].x*R[j].x + R[j].y*R[j].y) * scale;
    float xv = xr[n];
    o[n]        = xv;
    o[n + HW]   = y;
    o[n + 2*HW] = fabsf(y - xv);
  }
  if (slice == 0 && b < 8){                 // PI tail: 8192 floats
    const float4* p4 = (const float4*)pi;
    float4* o4 = (float4*)out;
    o4[6291456 + b*256 + tid] = p4[b*256 + tid];
  }
}

// ---------------- K3 (fallback): row inverse + abs -> y into ch0 ----------------
__global__ __launch_bounds__(256) void k_row_inv_stage(const float2* __restrict__ S, int bstride,
                                                       float* __restrict__ out){
  __shared__ float2 tw[256];
  __shared__ float2 zbuf[16*273];
  int tid = threadIdx.x;
  int s = tid & 15, r = tid >> 4;
  int slice = blockIdx.x, b = blockIdx.y;
  build_tw256(tw, tid);
  int h = slice*16 + r;
  const float4* src4 = (const float4*)(S + (size_t)b*bstride + h*256 + s*16);
  float2 X[16];
  #pragma unroll
  for (int k=0;k<8;++k){
    float4 v = src4[k];
    X[2*k]   = make_float2(v.x, v.y);
    X[2*k+1] = make_float2(v.z, v.w);
  }
  __syncthreads();
  fft16<true>(X);
  #pragma unroll
  for (int u=0;u<16;++u) X[u] = cmul_t<true>(X[u], tw[u*s]);
  #pragma unroll
  for (int u=0;u<16;++u) zbuf[r*273 + u*17 + s] = X[u];
  __syncthreads();
  int t = tid & 15;
  float2 R[16];
  #pragma unroll
  for (int k0=0;k0<16;++k0) R[k0] = zbuf[r*273 + t*17 + k0];
  fft16<true>(R);
  const float scale = 1.0f/65536.0f;
  float* o = out + (size_t)b*OUT_B_STRIDE + h*256;
  #pragma unroll
  for (int j=0;j<16;++j){
    int n = 16*j + t;
    o[n] = sqrtf(R[j].x*R[j].x + R[j].y*R[j].y) * scale;
  }
}

// ---------------- K4 (fallback): finalize ----------------
__global__ __launch_bounds__(256) void k_final(const float* __restrict__ x,
                                               const float* __restrict__ pi,
                                               float* __restrict__ out) {
  int i = blockIdx.x * 256 + threadIdx.x;     // float4 index over B*HW/4
  const float4* x4 = (const float4*)x;
  float4* o4 = (float4*)out;
  int b = i >> 14;
  int r = i & 16383;
  int ch0 = b * 49152 + r;
  float4 y  = o4[ch0];
  float4 xv = x4[i];
  float4 df;
  df.x = fabsf(y.x - xv.x);
  df.y = fabsf(y.y - xv.y);
  df.z = fabsf(y.z - xv.z);
  df.w = fabsf(y.w - xv.w);
  o4[ch0]         = xv;
  o4[ch0 + 16384] = y;
  o4[ch0 + 32768] = df;
  if (i < 2048) {
    const float4* p4 = (const float4*)pi;
    o4[6291456 + i] = p4[i];
  }
}

extern "C" void kernel_launch(void* const* d_in, const int* in_sizes, int n_in,
                              void* d_out, int out_size, void* d_ws, size_t ws_size,
                              hipStream_t stream) {
  const float* x  = (const float*)d_in[0];
  const float* pi = (const float*)d_in[1];
  const int*  cid = (const int*)d_in[2];
  float* out = (float*)d_out;
  (void)in_sizes; (void)n_in; (void)out_size;

  const size_t S_bytes = (size_t)BB * HW * sizeof(float2);   // 64 MB spectrum scratch
  if (ws_size >= S_bytes) {
    float2* S = (float2*)d_ws;
    k_row_fwd<<<2048, 256, 0, stream>>>(x, S, 65536);
    k_col<<<dim3(16, BB), 256, 0, stream>>>(S, 65536, cid, pi);
    k_row_inv_fused<<<dim3(16, BB), 256, 0, stream>>>(S, 65536, x, pi, out);
  } else {
    // spectrum aliased into out ch1+ch2; y staged in ch0; separate finalize
    float2* S = (float2*)out + 32768;
    k_row_fwd<<<2048, 256, 0, stream>>>(x, S, 98304);
    k_col<<<dim3(16, BB), 256, 0, stream>>>(S, 98304, cid, pi);
    k_row_inv_stage<<<dim3(16, BB), 256, 0, stream>>>(S, 98304, out);
    k_final<<<8192, 256, 0, stream>>>(x, pi, out);
  }
}

// Round 3
// 176.294 us; speedup vs baseline: 1.4361x; 1.1795x over previous
//
#include <hip/hip_runtime.h>
#include <hip/hip_fp16.h>
#include <math.h>

#define BB 128
#define HH 256
#define WW 256
#define HW 65536
#define OUT_B_STRIDE 196608   // 3*HW floats per batch in out

__device__ __forceinline__ float2 cadd(float2 a, float2 b){ return make_float2(a.x+b.x, a.y+b.y); }
__device__ __forceinline__ float2 csub(float2 a, float2 b){ return make_float2(a.x-b.x, a.y-b.y); }

// a * b  (INV=false)  or  a * conj(b)  (INV=true)
template<bool INV>
__device__ __forceinline__ float2 cmul_t(float2 a, float2 b){
  if (INV) return make_float2(a.x*b.x + a.y*b.y, a.y*b.x - a.x*b.y);
  return make_float2(a.x*b.x - a.y*b.y, a.x*b.y + a.y*b.x);
}

template<bool INV>
__device__ __forceinline__ void fft4(float2&a,float2&b,float2&c,float2&d){
  float2 t0 = cadd(a,c), t1 = csub(a,c);
  float2 t2 = cadd(b,d), t3 = csub(b,d);
  float2 t3r = INV ? make_float2(-t3.y, t3.x) : make_float2(t3.y, -t3.x);
  a = cadd(t0,t2);
  b = cadd(t1,t3r);
  c = csub(t0,t2);
  d = csub(t1,t3r);
}

// 16-point DFT, natural-in natural-out, exponent e^{-2pi i jq/16} (conj if INV).
template<bool INV>
__device__ __forceinline__ void fft16(float2 x[16]){
  #pragma unroll
  for (int j0=0;j0<4;++j0) fft4<INV>(x[j0], x[j0+4], x[j0+8], x[j0+12]);
  const float WR[10] = {1.f, 0.923879533f, 0.707106781f, 0.382683432f, 0.f,
                        0.f, -0.707106781f, 0.f, 0.f, -0.923879533f};
  const float WI[10] = {0.f, -0.382683432f, -0.707106781f, -0.923879533f, -1.f,
                        0.f, -0.707106781f, 0.f, 0.f, 0.382683432f};
  #pragma unroll
  for (int q0=1;q0<4;++q0)
    #pragma unroll
    for (int j0=1;j0<4;++j0){
      int k = j0*q0;
      x[j0+4*q0] = cmul_t<INV>(x[j0+4*q0], make_float2(WR[k], WI[k]));
    }
  #pragma unroll
  for (int q0=0;q0<4;++q0) fft4<INV>(x[4*q0], x[4*q0+1], x[4*q0+2], x[4*q0+3]);
  float2 t[16];
  #pragma unroll
  for (int q0=0;q0<4;++q0)
    #pragma unroll
    for (int q1=0;q1<4;++q1) t[q0+4*q1] = x[4*q0+q1];
  #pragma unroll
  for (int i=0;i<16;++i) x[i]=t[i];
}

__device__ __forceinline__ void build_tw256(float2* tw, int tid){
  float s,c;
  __sincosf(-6.28318530717958647692f * (float)tid / 256.0f, &s, &c);
  tw[tid] = make_float2(c, s);
}

__device__ __forceinline__ uint pkh2(float2 v){
  __half2 h = __float22half2_rn(v);
  return *(uint*)&h;
}
__device__ __forceinline__ float2 uph2(uint u){
  __half2 h = *(__half2*)&u;
  return __half22float2(h);
}

union SharedU {
  float  xs[16*272];     // 17408 B
  float2 zbuf[16*273];   // 34944 B
  float  ybuf[16*272];
};

// ---------------- K1: row forward FFT (+ cidp prep in first 64 blocks) ----------------
// 16 rows/block. Storage: S[b][h][p] __half2, p = s*16 + k1 encodes w_freq = 16*k1 + s.
__global__ __launch_bounds__(256, 4) void k_row_fwd(const float* __restrict__ x,
                                                    __half2* __restrict__ S,
                                                    const int* __restrict__ cid,
                                                    unsigned char* __restrict__ cidp){
  __shared__ SharedU sh;
  __shared__ float2 tw[256];
  int tid = threadIdx.x;
  int t = tid & 15, r = tid >> 4;
  build_tw256(tw, tid);

  // ---- cidp prep: cidp[p*256 + s*16 + k1] = cid[h2*256 + w2] ----
  if (blockIdx.x < 64){
    int g = (blockIdx.x*256 + tid) * 4;           // byte base
    int p  = g >> 8;
    int s  = (g >> 4) & 15;
    int k1b = g & 15;
    int wfreq = 16*(p & 15) + (p >> 4);
    int w2 = (wfreq + 128) & 255;
    uchar4 v4;
    unsigned char* vp = (unsigned char*)&v4;
    #pragma unroll
    for (int i=0;i<4;++i){
      int h2 = (16*(k1b+i) + s + 128) & 255;
      int cv = cid[h2*256 + w2];
      vp[i] = (unsigned char)cv;
    }
    *(uchar4*)(cidp + g) = v4;
  }

  // ---- stage x via float4 into LDS ----
  const float4* xb = (const float4*)x + (size_t)blockIdx.x * 1024;
  #pragma unroll
  for (int k=0;k<4;++k){
    int i2 = tid + k*256;
    float4 v = xb[i2];
    int row = i2 >> 6, c4 = i2 & 63;
    *(float4*)&sh.xs[row*272 + c4*4] = v;
  }
  __syncthreads();
  float2 X[16];
  #pragma unroll
  for (int j=0;j<16;++j) X[j] = make_float2(sh.xs[r*272 + 16*j + t], 0.f);
  __syncthreads();                       // xs reads done; zbuf may alias
  fft16<false>(X);
  #pragma unroll
  for (int q=0;q<16;++q) X[q] = cmul_t<false>(X[q], tw[t*q]);
  #pragma unroll
  for (int q=0;q<16;++q) sh.zbuf[r*273 + q*17 + t] = X[q];
  __syncthreads();
  float2 Y[16];
  #pragma unroll
  for (int tt=0;tt<16;++tt) Y[tt] = sh.zbuf[r*273 + t*17 + tt];   // s = t
  fft16<false>(Y);                       // Y[k1] = X256[16k1 + s]
  int row = blockIdx.x*16 + r;
  int b = row >> 8, h = row & 255;
  uint4* dst = (uint4*)(S + (size_t)b*HW + h*256 + t*16);
  #pragma unroll
  for (int k=0;k<4;++k){
    uint4 q;
    q.x = pkh2(Y[4*k+0]); q.y = pkh2(Y[4*k+1]);
    q.z = pkh2(Y[4*k+2]); q.w = pkh2(Y[4*k+3]);
    dst[k] = q;
  }
}

// ---------------- K2: column fwd + mask + column inv (in place) ----------------
__global__ __launch_bounds__(256, 4) void k_col(__half2* __restrict__ S,
                                                const unsigned char* __restrict__ cidp,
                                                const float* __restrict__ pi){
  __shared__ SharedU sh;
  __shared__ float2 tw[256];
  __shared__ float sPI[64];
  int tid = threadIdx.x;
  int c = tid & 15, t = tid >> 4;
  int cg = blockIdx.x, b = blockIdx.y;
  build_tw256(tw, tid);
  if (tid < 64) sPI[tid] = pi[(((b + 64) & 127) << 6) + tid] * 0.25f;  // batch-roll + 1/4 fold
  __half2* Sb = S + (size_t)b*HW;
  int p = cg*16 + c;
  float2 X[16];
  #pragma unroll
  for (int j=0;j<16;++j) X[j] = uph2(*(uint*)&Sb[(16*j + t)*256 + p]);
  // mask bytes for this (p, s=t): one 16B load
  uint4 mq = *(const uint4*)(cidp + p*256 + t*16);
  __syncthreads();
  fft16<false>(X);
  #pragma unroll
  for (int q=0;q<16;++q) X[q] = cmul_t<false>(X[q], tw[t*q]);
  #pragma unroll
  for (int q=0;q<16;++q) sh.zbuf[c*273 + q*17 + t] = X[q];
  __syncthreads();
  int s = t;
  float2 Y[16];
  #pragma unroll
  for (int tt=0;tt<16;++tt) Y[tt] = sh.zbuf[c*273 + s*17 + tt];
  fft16<false>(Y);                        // Y[k1] at h_freq = 16*k1 + s
  const uint* mw = (const uint*)&mq;
  #pragma unroll
  for (int k1=0;k1<16;++k1){
    int cv = (mw[k1>>2] >> ((k1&3)*8)) & 255;
    float m = (cv < 64) ? sPI[cv] : 0.25f;
    Y[k1].x *= m; Y[k1].y *= m;
  }
  __syncthreads();
  fft16<true>(Y);
  #pragma unroll
  for (int u=0;u<16;++u) Y[u] = cmul_t<true>(Y[u], tw[u*s]);
  #pragma unroll
  for (int u=0;u<16;++u) sh.zbuf[c*273 + u*17 + s] = Y[u];
  __syncthreads();
  float2 R[16];
  #pragma unroll
  for (int k0=0;k0<16;++k0) R[k0] = sh.zbuf[c*273 + t*17 + k0];
  fft16<true>(R);
  #pragma unroll
  for (int j=0;j<16;++j){
    uint u = pkh2(R[j]);
    *(uint*)&Sb[(16*j + t)*256 + p] = u;
  }
}

// ---------------- K3 (fused): row inverse + abs + finalize ----------------
__global__ __launch_bounds__(256, 4) void k_row_inv_fused(const __half2* __restrict__ S,
                                                          const float* __restrict__ x,
                                                          const float* __restrict__ pi,
                                                          float* __restrict__ out){
  __shared__ SharedU sh;
  __shared__ float2 tw[256];
  int tid = threadIdx.x;
  int s = tid & 15, r = tid >> 4;
  int slice = blockIdx.x, b = blockIdx.y;
  build_tw256(tw, tid);
  int h = slice*16 + r;
  const uint4* src = (const uint4*)(S + (size_t)b*HW + h*256 + s*16);
  float2 X[16];
  #pragma unroll
  for (int k=0;k<4;++k){
    uint4 q = src[k];
    X[4*k+0] = uph2(q.x); X[4*k+1] = uph2(q.y);
    X[4*k+2] = uph2(q.z); X[4*k+3] = uph2(q.w);
  }
  __syncthreads();
  fft16<true>(X);
  #pragma unroll
  for (int u=0;u<16;++u) X[u] = cmul_t<true>(X[u], tw[u*s]);
  #pragma unroll
  for (int u=0;u<16;++u) sh.zbuf[r*273 + u*17 + s] = X[u];
  __syncthreads();
  float2 R[16];
  #pragma unroll
  for (int k0=0;k0<16;++k0) R[k0] = sh.zbuf[r*273 + s*17 + k0];
  fft16<true>(R);
  __syncthreads();                          // zbuf reads done; ybuf aliases
  const float scale = 1.0f/16384.0f;        // 1/65536 * 4 (mask carried 1/4)
  #pragma unroll
  for (int j=0;j<16;++j)
    sh.ybuf[r*272 + 16*j + s] = sqrtf(R[j].x*R[j].x + R[j].y*R[j].y) * scale;
  __syncthreads();
  const float4* x4 = (const float4*)x;
  float4* o4 = (float4*)out;
  size_t xbase = (size_t)b*16384 + slice*1024;
  size_t obase = (size_t)b*49152 + slice*1024;
  #pragma unroll
  for (int k=0;k<4;++k){
    int i2 = tid + k*256;
    int rr = i2 >> 6, c4 = i2 & 63;
    float4 y = *(float4*)&sh.ybuf[rr*272 + c4*4];
    float4 xv = x4[xbase + i2];
    float4 df;
    df.x = fabsf(y.x - xv.x); df.y = fabsf(y.y - xv.y);
    df.z = fabsf(y.z - xv.z); df.w = fabsf(y.w - xv.w);
    o4[obase + i2]         = xv;
    o4[obase + i2 + 16384] = y;
    o4[obase + i2 + 32768] = df;
  }
  if (slice == 0 && b < 8){                 // PI tail: 8192 floats
    const float4* p4 = (const float4*)pi;
    o4[6291456 + b*256 + tid] = p4[b*256 + tid];
  }
}

// ---------------- K3 (fallback): row inverse + abs -> y into ch0 ----------------
__global__ __launch_bounds__(256, 4) void k_row_inv_stage(const __half2* __restrict__ S,
                                                          float* __restrict__ out){
  __shared__ SharedU sh;
  __shared__ float2 tw[256];
  int tid = threadIdx.x;
  int s = tid & 15, r = tid >> 4;
  int slice = blockIdx.x, b = blockIdx.y;
  build_tw256(tw, tid);
  int h = slice*16 + r;
  const uint4* src = (const uint4*)(S + (size_t)b*HW + h*256 + s*16);
  float2 X[16];
  #pragma unroll
  for (int k=0;k<4;++k){
    uint4 q = src[k];
    X[4*k+0] = uph2(q.x); X[4*k+1] = uph2(q.y);
    X[4*k+2] = uph2(q.z); X[4*k+3] = uph2(q.w);
  }
  __syncthreads();
  fft16<true>(X);
  #pragma unroll
  for (int u=0;u<16;++u) X[u] = cmul_t<true>(X[u], tw[u*s]);
  #pragma unroll
  for (int u=0;u<16;++u) sh.zbuf[r*273 + u*17 + s] = X[u];
  __syncthreads();
  float2 R[16];
  #pragma unroll
  for (int k0=0;k0<16;++k0) R[k0] = sh.zbuf[r*273 + s*17 + k0];
  fft16<true>(R);
  const float scale = 1.0f/16384.0f;
  float* o = out + (size_t)b*OUT_B_STRIDE + h*256;
  #pragma unroll
  for (int j=0;j<16;++j)
    o[16*j + s] = sqrtf(R[j].x*R[j].x + R[j].y*R[j].y) * scale;
}

// ---------------- K4 (fallback): finalize ----------------
__global__ __launch_bounds__(256) void k_final(const float* __restrict__ x,
                                               const float* __restrict__ pi,
                                               float* __restrict__ out) {
  int i = blockIdx.x * 256 + threadIdx.x;
  const float4* x4 = (const float4*)x;
  float4* o4 = (float4*)out;
  int b = i >> 14;
  int r = i & 16383;
  int ch0 = b * 49152 + r;
  float4 y  = o4[ch0];
  float4 xv = x4[i];
  float4 df;
  df.x = fabsf(y.x - xv.x);
  df.y = fabsf(y.y - xv.y);
  df.z = fabsf(y.z - xv.z);
  df.w = fabsf(y.w - xv.w);
  o4[ch0]         = xv;
  o4[ch0 + 16384] = y;
  o4[ch0 + 32768] = df;
  if (i < 2048) {
    const float4* p4 = (const float4*)pi;
    o4[6291456 + i] = p4[i];
  }
}

extern "C" void kernel_launch(void* const* d_in, const int* in_sizes, int n_in,
                              void* d_out, int out_size, void* d_ws, size_t ws_size,
                              hipStream_t stream) {
  const float* x  = (const float*)d_in[0];
  const float* pi = (const float*)d_in[1];
  const int*  cid = (const int*)d_in[2];
  float* out = (float*)d_out;
  (void)in_sizes; (void)n_in; (void)out_size;

  const size_t S_bytes = (size_t)BB * HW * sizeof(__half2);   // 32 MB
  const size_t cidp_bytes = 65536;

  if (ws_size >= S_bytes + cidp_bytes) {
    __half2* S = (__half2*)d_ws;
    unsigned char* cidp = (unsigned char*)d_ws + S_bytes;
    k_row_fwd<<<2048, 256, 0, stream>>>(x, S, cid, cidp);
    k_col<<<dim3(16, BB), 256, 0, stream>>>(S, cidp, pi);
    k_row_inv_fused<<<dim3(16, BB), 256, 0, stream>>>(S, x, pi, out);
  } else {
    // S aliased into out ch1 region (32MB of the 64MB ch1+ch2 span); y staged in ch0.
    __half2* S = (__half2*)((float*)out + HW);   // not per-batch disjoint; use global offset region
    // ch1+ch2 of batch-interleaved layout isn't contiguous; instead use the upper half of out:
    S = (__half2*)out + (size_t)BB * HW;         // floats [BB*HW .. BB*HW + BB*HW) = 32 MB region
    unsigned char* cidp = (unsigned char*)d_ws;  // needs 64 KB
    k_row_fwd<<<2048, 256, 0, stream>>>(x, S, cid, cidp);
    k_col<<<dim3(16, BB), 256, 0, stream>>>(S, cidp, pi);
    k_row_inv_stage<<<dim3(16, BB), 256, 0, stream>>>(S, out);
    k_final<<<8192, 256, 0, stream>>>(x, pi, out);
  }
}